// Round 14
// baseline (374.783 us; speedup 1.0000x reference)
//
#include <hip/hip_runtime.h>
#include <hip/hip_bf16.h>

// ---------------------------------------------------------------------------
// Transformer block: x + attn(LN1(x)) ; then x2 + proj(relu(fc(LN2(x2))))
// B=2, T=2048, C=1024, H=16, hd=64, MLP hidden 4096. All GEMMs bf16 MFMA.
// R24: R22 skeleton (287.0us proven) + ONE change: reduce_proj fused into the
//      proj gemm as a last-arriver finisher, now race-hardened: proj-only
//      block decode tt=8*(m&7)+c, bz=m>>3 puts ALL 4 split-K blocks of a
//      tile on the SAME XCD (tt&7==c) -> partials coherent in that XCD's L2;
//      threadfence + device-scope atomicAdd + threadfence is then a sound
//      release/acquire pair (R23's cross-XCD version raced, absmax 5.9).
//      Cooperative LN2 abandoned; ln_kernel restored. Launches 7 -> 6.
//      gemm256 = R22 4-phase counted-vmcnt. attn = R21 CU-paired.
// ---------------------------------------------------------------------------

typedef __bf16  bf16x8  __attribute__((ext_vector_type(8)));
typedef __bf16  bf16x4  __attribute__((ext_vector_type(4)));
typedef float   floatx4 __attribute__((ext_vector_type(4)));

#define T_LEN 2048
#define EMB   1024
#define NH    16
#define HD    64
#define HID   4096

#define GLOBAL_LOAD_LDS16(gp, lp) \
    __builtin_amdgcn_global_load_lds( \
        (const __attribute__((address_space(1))) void*)(gp), \
        (__attribute__((address_space(3))) void*)(lp), 16, 0, 0)

// ---------------- LN row helper: float4 loads, 256 threads -----------------
__device__ __forceinline__ void ln_row_f4(const float* __restrict__ in,
        const float* __restrict__ sc, const float* __restrict__ sh,
        __bf16* __restrict__ out, int row, float* ssum, float* ssum2) {
    int tid = threadIdx.x;
    int lane = tid & 63, wave = tid >> 6;
    float4 v = ((const float4*)(in + (size_t)row * EMB))[tid];
    float s  = v.x + v.y + v.z + v.w;
    float s2 = v.x * v.x + v.y * v.y + v.z * v.z + v.w * v.w;
    for (int m = 1; m < 64; m <<= 1) {
        s  += __shfl_xor(s, m);
        s2 += __shfl_xor(s2, m);
    }
    if (lane == 0) { ssum[wave] = s; ssum2[wave] = s2; }
    __syncthreads();
    float tot  = ssum[0] + ssum[1] + ssum[2] + ssum[3];
    float tot2 = ssum2[0] + ssum2[1] + ssum2[2] + ssum2[3];
    float mean = tot * (1.f / EMB);
    float rstd = rsqrtf(tot2 * (1.f / EMB) - mean * mean + 1e-5f);
    float4 sv = ((const float4*)sc)[tid];
    float4 hv = ((const float4*)sh)[tid];
    bf16x4 o;
    o[0] = (__bf16)((v.x - mean) * rstd * sv.x + hv.x);
    o[1] = (__bf16)((v.y - mean) * rstd * sv.y + hv.y);
    o[2] = (__bf16)((v.z - mean) * rstd * sv.z + hv.z);
    o[3] = (__bf16)((v.w - mean) * rstd * sv.w + hv.w);
    *(bf16x4*)(out + (size_t)row * EMB + tid * 4) = o;
}

// ---------------- prep: LN1 (blocks 0..4095) + 3x transpose (4096..15359) --
__global__ __launch_bounds__(256)
void prep_kernel(const float* __restrict__ x, const float* __restrict__ ln1_s,
                 const float* __restrict__ ln1_b, __bf16* __restrict__ h1,
                 const float* __restrict__ w_qkv, __bf16* __restrict__ o_qkv,
                 const float* __restrict__ w_fc,  __bf16* __restrict__ o_fc,
                 const float* __restrict__ w_pj,  __bf16* __restrict__ o_pj) {
    __shared__ float tile[32][33];
    __shared__ float ssum[4], ssum2[4];
    int bid = blockIdx.x;
    int tid = threadIdx.x;
    if (bid < 4096) {
        ln_row_f4(x, ln1_s, ln1_b, h1, bid, ssum, ssum2);
        return;
    }
    int b2 = bid - 4096;
    const float* in; __bf16* out; int R, C, bx, by;
    if (b2 < 3072)       { in = w_qkv; out = o_qkv; R = 1024; C = 3072;
                           bx = b2 % 96;  by = b2 / 96;  }
    else if (b2 < 7168)  { in = w_fc;  out = o_fc;  R = 1024; C = 4096;
                           int r = b2 - 3072; bx = r % 128; by = r / 128; }
    else                 { in = w_pj;  out = o_pj;  R = 4096; C = 1024;
                           int r = b2 - 7168; bx = r % 32;  by = r / 32;  }
    int bc = bx * 32, br = by * 32;
    int tx = tid & 31, ty = tid >> 5;
    for (int i = 0; i < 32; i += 8)
        tile[ty + i][tx] = in[(size_t)(br + ty + i) * C + bc + tx];
    __syncthreads();
    for (int i = 0; i < 32; i += 8) {
        int c = bc + ty + i, r = br + tx;
        out[(size_t)c * R + r] = (__bf16)tile[tx][ty + i];
    }
}

// ---------------- layernorm (standalone, for LN2) --------------------------
__global__ __launch_bounds__(256)
void ln_kernel(const float* __restrict__ in, const float* __restrict__ sc,
               const float* __restrict__ sh, __bf16* __restrict__ out) {
    __shared__ float ssum[4], ssum2[4];
    ln_row_f4(in, sc, sh, out, blockIdx.x, ssum, ssum2);
}

// ---------------- bf16 MFMA GEMM, BM=BN=256 BK=64, 4-phase counted-vmcnt ---
// R22 schedule (proven). ctr!=nullptr (proj split-K fused): PROJ DECODE puts
// all 4 bz-blocks of a tile on one XCD (tt=8*(m&7)+c, bz=m>>3; tt&7==c);
// partial writers: threadfence + atomicAdd(ctr[tt]); last arriver (old==3,
// zero spin) threadfences and reduces 4 bf16 partials + fx2 + fbias -> fout
// (float4), partials L2-hot (8 tiles x 512KB = 4MB per XCD).
__global__ __launch_bounds__(512)
void gemm256(const __bf16* __restrict__ A, const __bf16* __restrict__ Bt,
             const float* __restrict__ bias, const float* __restrict__ res,
             float* __restrict__ outF, __bf16* __restrict__ outB,
             int M, int N, int lda, int KL, int relu, int gx, int gz,
             unsigned* __restrict__ ctr, const float* __restrict__ fx2,
             const float* __restrict__ fbias, float* __restrict__ fout) {
    __shared__ __align__(16) __bf16 sA[2][256][64];
    __shared__ __align__(16) __bf16 sB[2][256][64];
    const int BUFE = 256 * 64;
    int tid  = threadIdx.x;
    int lane = tid & 63, wave = tid >> 6;
    int quad = lane >> 4, l16 = lane & 15;

    // Block decode. Default: pair p=(by*gz+bz) pinned to XCD p&7 (grid%8==0).
    // Proj-fused: tile tt on XCD tt&7, all 4 bz together.
    int i  = blockIdx.x;
    int c  = i & 7, m = i >> 3;
    int bx, by, bz;
    if (ctr) {
        int tt = ((m & 7) << 3) + c;   // 0..63, tt&7 == c
        bz = m >> 3;                   // 0..3
        by = tt >> 2;                  // 0..15
        bx = tt & 3;                   // 0..3
    } else {
        bx = m % gx;
        int p = (m / gx) * 8 + c;
        by = p / gz;
        bz = p - by * gz;
    }

    int bm = by * 256, bn = bx * 256;
    size_t k0 = (size_t)bz * KL;
    int wm = (wave >> 2) * 128, wn = (wave & 3) * 64;

    floatx4 acc[8][4] = {};

    int srow  = tid >> 3;
    int sslot = (tid & 7) ^ (srow & 7);
    const __bf16* gA = A  + (size_t)(bm + srow) * lda + k0 + sslot * 8;
    const __bf16* gB = Bt + (size_t)(bn + srow) * lda + k0 + sslot * 8;
    __bf16* lA = &sA[0][0][0] + wave * 512;
    __bf16* lB = &sB[0][0][0] + wave * 512;
    const size_t rstep = (size_t)64 * lda;

    // prologue: tile 0 all 8 chunks, drain once
    GLOBAL_LOAD_LDS16(gA,             lA);
    GLOBAL_LOAD_LDS16(gA + 2 * rstep, lA + 8192);
    GLOBAL_LOAD_LDS16(gB,             lB);
    GLOBAL_LOAD_LDS16(gB + rstep,     lB + 4096);
    GLOBAL_LOAD_LDS16(gB + 2 * rstep, lB + 8192);
    GLOBAL_LOAD_LDS16(gB + 3 * rstep, lB + 12288);
    GLOBAL_LOAD_LDS16(gA + rstep,     lA + 4096);
    GLOBAL_LOAD_LDS16(gA + 3 * rstep, lA + 12288);
    asm volatile("s_waitcnt vmcnt(0)" ::: "memory");
    __builtin_amdgcn_s_barrier();

    int xs0  = ((quad) ^ (l16 & 7)) * 8;
    int xs1  = ((4 + quad) ^ (l16 & 7)) * 8;
    int aoff = (wm + l16) * 64;
    int boff = (wn + l16) * 64;

#define PH_IN() do { __builtin_amdgcn_s_barrier(); \
    asm volatile("s_waitcnt lgkmcnt(0)" ::: "memory"); \
    __builtin_amdgcn_sched_barrier(0); } while (0)

    const int nt = KL / 64;
    for (int t = 0; t < nt; ++t) {
        const int cur  = t & 1;
        const int nb   = cur ^ 1;
        const bool more = (t + 1 < nt);
        const size_t ko = (size_t)(t + 1) * 64;
        const __bf16* sAc = &sA[0][0][0] + cur * BUFE;
        const __bf16* sBc = &sB[0][0][0] + cur * BUFE;

        bf16x8 a0[4][2], a1[4][2], b0[2][2], b1[2][2];

        // ---- phase 1: ds a0(8)+b0(4); stage c0,c1; MFMA a0xb0
        #pragma unroll
        for (int mi = 0; mi < 4; ++mi) {
            a0[mi][0] = *(const bf16x8*)(sAc + aoff + mi * 1024 + xs0);
            a0[mi][1] = *(const bf16x8*)(sAc + aoff + mi * 1024 + xs1);
        }
        #pragma unroll
        for (int nj = 0; nj < 2; ++nj) {
            b0[nj][0] = *(const bf16x8*)(sBc + boff + nj * 1024 + xs0);
            b0[nj][1] = *(const bf16x8*)(sBc + boff + nj * 1024 + xs1);
        }
        if (more) {
            GLOBAL_LOAD_LDS16(gA + ko,             lA + nb * BUFE);
            GLOBAL_LOAD_LDS16(gA + ko + 2 * rstep, lA + nb * BUFE + 8192);
        }
        PH_IN();
        __builtin_amdgcn_s_setprio(1);
        #pragma unroll
        for (int ks = 0; ks < 2; ++ks)
            #pragma unroll
            for (int mi = 0; mi < 4; ++mi)
                #pragma unroll
                for (int nj = 0; nj < 2; ++nj)
                    acc[mi][nj] = __builtin_amdgcn_mfma_f32_16x16x32_bf16(
                        a0[mi][ks], b0[nj][ks], acc[mi][nj], 0, 0, 0);
        __builtin_amdgcn_s_setprio(0);
        __builtin_amdgcn_s_barrier();

        // ---- phase 2: ds b1(4); stage c2,c3; vmcnt(4|0); MFMA a0xb1
        #pragma unroll
        for (int nj = 0; nj < 2; ++nj) {
            b1[nj][0] = *(const bf16x8*)(sBc + boff + (2 + nj) * 1024 + xs0);
            b1[nj][1] = *(const bf16x8*)(sBc + boff + (2 + nj) * 1024 + xs1);
        }
        if (more) {
            GLOBAL_LOAD_LDS16(gB + ko,         lB + nb * BUFE);
            GLOBAL_LOAD_LDS16(gB + ko + rstep, lB + nb * BUFE + 4096);
            asm volatile("s_waitcnt vmcnt(4)" ::: "memory");
        } else {
            asm volatile("s_waitcnt vmcnt(0)" ::: "memory");
        }
        PH_IN();
        __builtin_amdgcn_s_setprio(1);
        #pragma unroll
        for (int ks = 0; ks < 2; ++ks)
            #pragma unroll
            for (int mi = 0; mi < 4; ++mi)
                #pragma unroll
                for (int nj = 0; nj < 2; ++nj)
                    acc[mi][2 + nj] = __builtin_amdgcn_mfma_f32_16x16x32_bf16(
                        a0[mi][ks], b1[nj][ks], acc[mi][2 + nj], 0, 0, 0);
        __builtin_amdgcn_s_setprio(0);
        __builtin_amdgcn_s_barrier();

        // ---- phase 3: ds a1(8); stage c4,c5; MFMA a1xb1
        #pragma unroll
        for (int mi = 0; mi < 4; ++mi) {
            a1[mi][0] = *(const bf16x8*)(sAc + aoff + (4 + mi) * 1024 + xs0);
            a1[mi][1] = *(const bf16x8*)(sAc + aoff + (4 + mi) * 1024 + xs1);
        }
        if (more) {
            GLOBAL_LOAD_LDS16(gB + ko + 2 * rstep, lB + nb * BUFE + 8192);
            GLOBAL_LOAD_LDS16(gB + ko + 3 * rstep, lB + nb * BUFE + 12288);
        }
        PH_IN();
        __builtin_amdgcn_s_setprio(1);
        #pragma unroll
        for (int ks = 0; ks < 2; ++ks)
            #pragma unroll
            for (int mi = 0; mi < 4; ++mi)
                #pragma unroll
                for (int nj = 0; nj < 2; ++nj)
                    acc[4 + mi][2 + nj] = __builtin_amdgcn_mfma_f32_16x16x32_bf16(
                        a1[mi][ks], b1[nj][ks], acc[4 + mi][2 + nj], 0, 0, 0);
        __builtin_amdgcn_s_setprio(0);
        __builtin_amdgcn_s_barrier();

        // ---- phase 4: stage c6,c7; vmcnt(2|0); barrier; MFMA a1xb0
        if (more) {
            GLOBAL_LOAD_LDS16(gA + ko + rstep,     lA + nb * BUFE + 4096);
            GLOBAL_LOAD_LDS16(gA + ko + 3 * rstep, lA + nb * BUFE + 12288);
            asm volatile("s_waitcnt vmcnt(2)" ::: "memory");
        } else {
            asm volatile("s_waitcnt vmcnt(0)" ::: "memory");
        }
        __builtin_amdgcn_s_barrier();
        asm volatile("" ::: "memory");
        __builtin_amdgcn_s_setprio(1);
        #pragma unroll
        for (int ks = 0; ks < 2; ++ks)
            #pragma unroll
            for (int mi = 0; mi < 4; ++mi)
                #pragma unroll
                for (int nj = 0; nj < 2; ++nj)
                    acc[4 + mi][nj] = __builtin_amdgcn_mfma_f32_16x16x32_bf16(
                        a1[mi][ks], b0[nj][ks], acc[4 + mi][nj], 0, 0, 0);
        __builtin_amdgcn_s_setprio(0);
    }
#undef PH_IN

    if (bias) {
        #pragma unroll
        for (int mi = 0; mi < 8; ++mi) {
            int row0 = bm + wm + mi * 16 + quad * 4;
            #pragma unroll
            for (int nj = 0; nj < 4; ++nj) {
                int col = bn + wn + nj * 16 + l16;
                float bv = bias[col];
                #pragma unroll
                for (int r = 0; r < 4; ++r) {
                    size_t idx = (size_t)(row0 + r) * N + col;
                    float cc = acc[mi][nj][r] + bv;
                    if (relu) cc = fmaxf(cc, 0.f);
                    if (res)  cc += res[idx];
                    if (outF) outF[idx] = cc;
                    if (outB) outB[idx] = (__bf16)cc;
                }
            }
        }
    } else {
        __bf16* po = outB + (size_t)bz * M * N;
        #pragma unroll
        for (int mi = 0; mi < 8; ++mi) {
            int row0 = bm + wm + mi * 16 + quad * 4;
            #pragma unroll
            for (int nj = 0; nj < 4; ++nj) {
                int col = bn + wn + nj * 16 + l16;
                #pragma unroll
                for (int r = 0; r < 4; ++r)
                    po[(size_t)(row0 + r) * N + col] = (__bf16)acc[mi][nj][r];
            }
        }
        if (ctr) {
            // last-arriver finisher (same-XCD partials): reduce once all 4
            // bz-blocks of this tile have published.
            __shared__ unsigned oldv;
            __threadfence();           // release: publish my partial stores
            __syncthreads();           // all threads' stores+fence done
            if (tid == 0) oldv = atomicAdd(&ctr[(by << 2) + bx], 1u);
            __syncthreads();
            if (oldv == 3) {
                __threadfence();       // acquire: see peers' partials (same L2)
                const int NF4 = 256 * 64;        // 256 rows x 64 float4
                for (int e = tid; e < NF4; e += 512) {
                    int r  = e >> 6, c4 = (e & 63) * 4;
                    size_t base = (size_t)(bm + r) * N + bn + c4;
                    float4 xv = *(const float4*)(fx2 + base);
                    float4 bb = *(const float4*)(fbias + bn + c4);
                    float a0v = xv.x + bb.x, a1v = xv.y + bb.y;
                    float a2v = xv.z + bb.z, a3v = xv.w + bb.w;
                    #pragma unroll
                    for (int k = 0; k < 4; ++k) {
                        bf16x4 pv = *(const bf16x4*)
                            (outB + (size_t)k * M * N + base);
                        a0v += (float)pv[0]; a1v += (float)pv[1];
                        a2v += (float)pv[2]; a3v += (float)pv[3];
                    }
                    float4 o = {a0v, a1v, a2v, a3v};
                    *(float4*)(fout + base) = o;
                }
            }
        }
    }
}

// ---------------- bf16 MFMA GEMM (BM=128, BN=64) — ws-fallback only --------
__global__ __launch_bounds__(256)
void gemm_bt_n64(const __bf16* __restrict__ A, const __bf16* __restrict__ Bt,
                 const float* __restrict__ bias, const float* __restrict__ res,
                 float* __restrict__ outF, __bf16* __restrict__ outB,
                 int M, int N, int K, int relu) {
    __shared__ __align__(16) __bf16 sA[128][40];
    __shared__ __align__(16) __bf16 sB[64][40];
    int tid  = threadIdx.x;
    int lane = tid & 63, wave = tid >> 6;
    int quad = lane >> 4, l16 = lane & 15;
    int bm = blockIdx.y * 128, bn = blockIdx.x * 64;
    int wm = (wave & 1) * 64, wn = (wave >> 1) * 32;
    floatx4 acc[4][2] = {};

    int srow = tid >> 2;
    int scol = (tid & 3) * 8;
    const __bf16* gA = &A[(size_t)(bm + srow) * K + scol];
    const __bf16* gB = &Bt[(size_t)(bn + srow) * K + scol];

    uint4 ra0 = *(const uint4*)gA;
    uint4 ra1 = *(const uint4*)(gA + (size_t)64 * K);
    uint4 rb0 = *(const uint4*)gB;

    for (int kk = 0; kk < K; kk += 32) {
        __syncthreads();
        *(uint4*)&sA[srow][scol]      = ra0;
        *(uint4*)&sA[srow + 64][scol] = ra1;
        *(uint4*)&sB[srow][scol]      = rb0;
        __syncthreads();
        {
            int kn = (kk + 32 < K) ? kk + 32 : kk;
            ra0 = *(const uint4*)(gA + kn);
            ra1 = *(const uint4*)(gA + kn + (size_t)64 * K);
            rb0 = *(const uint4*)(gB + kn);
        }
        bf16x8 af[4], bfr[2];
        for (int i = 0; i < 4; i++)
            af[i] = *(const bf16x8*)&sA[wm + i * 16 + l16][quad * 8];
        for (int j = 0; j < 2; j++)
            bfr[j] = *(const bf16x8*)&sB[wn + j * 16 + l16][quad * 8];
        for (int i = 0; i < 4; i++)
            for (int j = 0; j < 2; j++)
                acc[i][j] = __builtin_amdgcn_mfma_f32_16x16x32_bf16(
                    af[i], bfr[j], acc[i][j], 0, 0, 0);
    }

    for (int i = 0; i < 4; i++) {
        int row0 = bm + wm + i * 16 + quad * 4;
        for (int j = 0; j < 2; j++) {
            int col = bn + wn + j * 16 + l16;
            float bv = bias[col];
            for (int r = 0; r < 4; r++) {
                size_t idx = (size_t)(row0 + r) * N + col;
                float c = acc[i][j][r] + bv;
                if (relu) c = fmaxf(c, 0.f);
                if (res)  c += res[idx];
                if (outF) outF[idx] = c;
                if (outB) outB[idx] = (__bf16)c;
            }
        }
    }
}

// ---------------- flash attention: CU-balanced complementary pairs --------
// grid 512: i -> XCD c=i&7, m=i>>3. Dispatch model: XCD x receives m=j in
// order; CU k hosts j=k and j=k+32. pair=(j<8)?j:23-j -> CU runs pairs
// (q, 15-q): 49 iterations on EVERY CU. Waves 0-3 heavy qt_h=31-pair,
// waves 4-7 light=pair (16 rows/wave); light group skips past-diagonal
// tiles (wave-uniform, barriers outside). Softmax fixed-max exp2,
// wave-private sP. T5 setprio(1) around QK/PV MFMA clusters.
__global__ __launch_bounds__(512)
void attn_kernel(const __bf16* __restrict__ qkv, const float* __restrict__ x,
                 float* __restrict__ x2) {
    __shared__ __align__(16) __bf16 sK[2][64][72];
    __shared__ __align__(16) __bf16 sVt[2][64][72];
    __shared__ __align__(16) __bf16 sP[8][16][72];
    const int tid  = threadIdx.x;
    const int lane = tid & 63, wave = tid >> 6;
    const int quad = lane >> 4, l16 = lane & 15;

    int i = blockIdx.x;
    int c = i & 7, m = i >> 3;
    const int bh   = (m & 3) * 8 + c;          // 0..31, XCD-pinned
    const int j_   = m >> 2;                   // 0..15 dispatch-order index
    const int pair = (j_ < 8) ? j_ : 23 - j_;  // CU-balanced bijection
    const int qt_h = 31 - pair;                // heavy q-tile, 16..31
    const int h    = bh & (NH - 1);
    const int b    = bh >> 4;
    const size_t rowbase = (size_t)b * T_LEN;

    const int g  = wave >> 2;                  // 0 = heavy group, 1 = light
    const int wg = wave & 3;
    const int qt = g ? pair : qt_h;            // this group's q-tile
    const int qrow = qt * 64 + wg * 16;        // this wave's 16 q rows
    const int dt   = qt;                       // group's diagonal K-tile

    const float kQScale = 0.125f * 1.44269504088896f;
    bf16x8 ones;
    for (int j = 0; j < 8; j++) ones[j] = (__bf16)1.0f;

    // staging: 512 threads cover 64 keys x 8 chunks, one uint4 each
    const int key0 = tid >> 3, m8 = tid & 7;
    const __bf16* kp0 = qkv + (rowbase + key0) * 3072 + h * HD + m8 * 8 + 1024;
    const int pc0 = ((key0 >> 3) ^ m8) * 8 + (key0 & 7);

    bf16x8 qf[2];
    for (int ks = 0; ks < 2; ks++) {
        bf16x8 raw = *(const bf16x8*)&qkv[(rowbase + qrow + l16) * 3072
                                          + h * HD + ks * 32 + quad * 8];
        for (int j = 0; j < 8; j++)
            qf[ks][j] = (__bf16)((float)raw[j] * kQScale);
    }

    floatx4 o[4] = {}, ol = {};

    const int ntiles = qt_h + 1;               // 17..32
    const size_t TSTEP = (size_t)64 * 3072;

    // prologue: tile 0 -> regs -> buf0 ; tile 1 -> regs ; barrier
    uint4 kr0 = *(const uint4*)kp0;
    uint4 vr0 = *(const uint4*)(kp0 + 1024);
    {
        *(uint4*)&sK[0][key0][m8 * 8] = kr0;
        bf16x8 v0 = *(bf16x8*)&vr0;
        for (int j = 0; j < 8; j++) sVt[0][m8 * 8 + j][pc0] = v0[j];
    }
    kr0 = *(const uint4*)(kp0 + TSTEP);            // ntiles >= 17 always
    vr0 = *(const uint4*)(kp0 + TSTEP + 1024);
    __syncthreads();

    for (int kt = 0; kt < ntiles; kt++) {
        const int cur = kt & 1, nxt = cur ^ 1;
        if (kt + 1 < ntiles) {
            *(uint4*)&sK[nxt][key0][m8 * 8] = kr0;
            bf16x8 v0 = *(bf16x8*)&vr0;
            for (int j = 0; j < 8; j++) sVt[nxt][m8 * 8 + j][pc0] = v0[j];
            size_t offn = (size_t)((kt + 2 < ntiles) ? kt + 2 : kt + 1) * TSTEP;
            kr0 = *(const uint4*)(kp0 + offn);
            vr0 = *(const uint4*)(kp0 + offn + 1024);
        }

        if (kt <= dt) {
            // S = Q K^T (exp2 domain) from buf[cur]
            floatx4 s_acc[4] = {};
            __builtin_amdgcn_s_setprio(1);
            for (int jt = 0; jt < 4; jt++)
                for (int ks = 0; ks < 2; ks++) {
                    bf16x8 kf = *(const bf16x8*)&sK[cur][jt * 16 + l16]
                                                  [ks * 32 + quad * 8];
                    s_acc[jt] = __builtin_amdgcn_mfma_f32_16x16x32_bf16(
                        qf[ks], kf, s_acc[jt], 0, 0, 0);
                }
            __builtin_amdgcn_s_setprio(0);

            // P = exp2(min(s,30)); mask only on this group's diagonal tile.
            if (kt == dt) {
                const int tq0 = qrow + quad * 4;
                const int k0 = kt * 64;
                for (int jt = 0; jt < 4; jt++) {
                    int key = k0 + jt * 16 + l16;
                    for (int r = 0; r < 4; r++) {
                        float sv = (key <= tq0 + r) ? s_acc[jt][r] : -1e30f;
                        float pv = __builtin_amdgcn_exp2f(fminf(sv, 30.f));
                        sP[wave][quad * 4 + r][jt * 16 + l16] = (__bf16)pv;
                    }
                }
            } else {
                for (int jt = 0; jt < 4; jt++)
                    for (int r = 0; r < 4; r++) {
                        float pv = __builtin_amdgcn_exp2f(fminf(s_acc[jt][r], 30.f));
                        sP[wave][quad * 4 + r][jt * 16 + l16] = (__bf16)pv;
                    }
            }
            // sP wave-private: lgkmcnt ordering suffices, no barrier.

            for (int kp = 0; kp < 2; kp++) {
                bf16x8 pf = *(const bf16x8*)&sP[wave][l16][kp * 32 + quad * 8];
                __builtin_amdgcn_s_setprio(1);
                ol = __builtin_amdgcn_mfma_f32_16x16x32_bf16(pf, ones, ol, 0, 0, 0);
                for (int jt2 = 0; jt2 < 4; jt2++) {
                    int d = jt2 * 16 + l16;
                    int pg = (kp * 4 + quad) ^ (d >> 3);
                    bf16x8 vf = *(const bf16x8*)&sVt[cur][d][pg * 8];
                    o[jt2] = __builtin_amdgcn_mfma_f32_16x16x32_bf16(
                        pf, vf, o[jt2], 0, 0, 0);
                }
                __builtin_amdgcn_s_setprio(0);
            }
        }
        __syncthreads();   // all waves done reading cur & writing nxt
    }

    float inv[4];
    for (int r = 0; r < 4; r++) inv[r] = __builtin_amdgcn_rcpf(ol[r]);
    for (int jt2 = 0; jt2 < 4; jt2++) {
        for (int r = 0; r < 4; r++) {
            int tq  = qrow + quad * 4 + r;
            int col = h * HD + jt2 * 16 + l16;
            size_t gi = (rowbase + tq) * EMB + col;
            x2[gi] = x[gi] + o[jt2][r] * inv[r];
        }
    }
}

// ---------------------------------------------------------------------------
extern "C" void kernel_launch(void* const* d_in, const int* in_sizes, int n_in,
                              void* d_out, int out_size, void* d_ws, size_t ws_size,
                              hipStream_t stream) {
    const float* x      = (const float*)d_in[0];
    const float* ln1_s  = (const float*)d_in[1];
    const float* ln1_b  = (const float*)d_in[2];
    const float* w_qkv  = (const float*)d_in[3];
    const float* b_qkv  = (const float*)d_in[4];
    const float* ln2_s  = (const float*)d_in[5];
    const float* ln2_b  = (const float*)d_in[6];
    const float* w_fc   = (const float*)d_in[7];
    const float* b_fc   = (const float*)d_in[8];
    const float* w_proj = (const float*)d_in[9];
    const float* b_proj = (const float*)d_in[10];
    float* out = (float*)d_out;

    const int M = 2 * T_LEN;  // 4096 rows
    char* ws = (char*)d_ws;
    size_t off = 0;
    auto alloc = [&](size_t bytes) {
        void* p = ws + off; off += (bytes + 255) & ~(size_t)255; return p;
    };
    // alive through proj:
    __bf16* wpj_t  = (__bf16*)alloc((size_t)1024 * 4096 * 2);
    float*  x2     = (float*) alloc((size_t)M * 1024 * 4);
    __bf16* hfc    = (__bf16*)alloc((size_t)M * 4096 * 2);
    unsigned* ctr  = (unsigned*)alloc(64 * sizeof(unsigned));
    size_t mark = off;                    // dead-by-proj region starts here
    __bf16* wqkv_t = (__bf16*)alloc((size_t)3072 * 1024 * 2);
    __bf16* wfc_t  = (__bf16*)alloc((size_t)4096 * 1024 * 2);
    __bf16* h1     = (__bf16*)alloc((size_t)M * 1024 * 2);
    __bf16* h2     = (__bf16*)alloc((size_t)M * 1024 * 2);
    __bf16* qkvb   = (__bf16*)alloc((size_t)M * 3072 * 2);
    // split-K bf16 partials overlay the dead region.
    __bf16* pbuf = (__bf16*)(ws + mark);
    size_t need = mark + (size_t)4 * M * 1024 * 2;
    bool can_split = ws_size >= need;

    // LN1 + 3x weight transpose fused (independent work, one launch)
    prep_kernel<<<15360, 256, 0, stream>>>(x, ln1_s, ln1_b, h1,
                                           w_qkv, wqkv_t, w_fc, wfc_t,
                                           w_proj, wpj_t);

    // qkv = LN1(x) @ w_qkv + b_qkv -> bf16 ; grid 16x12 flattened (192)
    gemm256<<<192, 512, 0, stream>>>(
        h1, wqkv_t, b_qkv, nullptr, nullptr, qkvb, M, 3072, 1024, 1024, 0,
        12, 1, nullptr, nullptr, nullptr, nullptr);

    attn_kernel<<<512, 512, 0, stream>>>(qkvb, x, x2);

    ln_kernel<<<M, 256, 0, stream>>>(x2, ln2_s, ln2_b, h2);

    // hfc = relu(h2 @ w_fc + b_fc) -> bf16 ; grid 16x16 flattened (256)
    gemm256<<<256, 512, 0, stream>>>(
        h2, wfc_t, b_fc, nullptr, nullptr, hfc, M, 4096, 1024, 1024, 1,
        16, 1, nullptr, nullptr, nullptr, nullptr);

    if (can_split) {
        // proj partials + same-XCD last-arriver reduce: grid 256
        hipMemsetAsync(ctr, 0, 64 * sizeof(unsigned), stream);
        gemm256<<<256, 512, 0, stream>>>(
            hfc, wpj_t, nullptr, nullptr, nullptr, pbuf, M, 1024, 4096, 1024, 0,
            4, 4, ctr, x2, b_proj, out);
    } else {
        gemm_bt_n64<<<dim3(1024 / 64, M / 128), 256, 0, stream>>>(
            hfc, wpj_t, b_proj, x2, out, nullptr, M, 1024, 4096, 0);
    }
}

// Round 15
// 286.118 us; speedup vs baseline: 1.3099x; 1.3099x over previous
//
#include <hip/hip_runtime.h>
#include <hip/hip_bf16.h>

// ---------------------------------------------------------------------------
// Transformer block: x + attn(LN1(x)) ; then x2 + proj(relu(fc(LN2(x2))))
// B=2, T=2048, C=1024, H=16, hd=64, MLP hidden 4096. All GEMMs bf16 MFMA.
// R25 = R22 revert (proven 287.0us). Lessons R23/R24 (both reverted):
//   - split-K finisher fusion: cross-XCD partials race (R23 absmax 5.9);
//     same-XCD-per-tile mapping fixes correctness but breaks the per-XCD
//     fixed-bz K-chunk locality (R22: bz=c&3) -> FETCH 28.8->98.4MB,
//     proj 46->138us (R24). Fusion line closed.
//   - cooperative LN2: abandoned with R23.
// Current structure: prep(LN1+3 transposes) -> gemm256 QKV -> attn(CU-paired
// complementary blocks, setprio) -> LN2 -> gemm256 FC -> gemm256 proj
// (split-K 4, bf16 partials) -> reduce_proj. gemm256 = 4-phase counted-vmcnt.
// ---------------------------------------------------------------------------

typedef __bf16  bf16x8  __attribute__((ext_vector_type(8)));
typedef __bf16  bf16x4  __attribute__((ext_vector_type(4)));
typedef float   floatx4 __attribute__((ext_vector_type(4)));

#define T_LEN 2048
#define EMB   1024
#define NH    16
#define HD    64
#define HID   4096

#define GLOBAL_LOAD_LDS16(gp, lp) \
    __builtin_amdgcn_global_load_lds( \
        (const __attribute__((address_space(1))) void*)(gp), \
        (__attribute__((address_space(3))) void*)(lp), 16, 0, 0)

// ---------------- LN row helper: float4 loads, 256 threads -----------------
__device__ __forceinline__ void ln_row_f4(const float* __restrict__ in,
        const float* __restrict__ sc, const float* __restrict__ sh,
        __bf16* __restrict__ out, int row, float* ssum, float* ssum2) {
    int tid = threadIdx.x;
    int lane = tid & 63, wave = tid >> 6;
    float4 v = ((const float4*)(in + (size_t)row * EMB))[tid];
    float s  = v.x + v.y + v.z + v.w;
    float s2 = v.x * v.x + v.y * v.y + v.z * v.z + v.w * v.w;
    for (int m = 1; m < 64; m <<= 1) {
        s  += __shfl_xor(s, m);
        s2 += __shfl_xor(s2, m);
    }
    if (lane == 0) { ssum[wave] = s; ssum2[wave] = s2; }
    __syncthreads();
    float tot  = ssum[0] + ssum[1] + ssum[2] + ssum[3];
    float tot2 = ssum2[0] + ssum2[1] + ssum2[2] + ssum2[3];
    float mean = tot * (1.f / EMB);
    float rstd = rsqrtf(tot2 * (1.f / EMB) - mean * mean + 1e-5f);
    float4 sv = ((const float4*)sc)[tid];
    float4 hv = ((const float4*)sh)[tid];
    bf16x4 o;
    o[0] = (__bf16)((v.x - mean) * rstd * sv.x + hv.x);
    o[1] = (__bf16)((v.y - mean) * rstd * sv.y + hv.y);
    o[2] = (__bf16)((v.z - mean) * rstd * sv.z + hv.z);
    o[3] = (__bf16)((v.w - mean) * rstd * sv.w + hv.w);
    *(bf16x4*)(out + (size_t)row * EMB + tid * 4) = o;
}

// ---------------- prep: LN1 (blocks 0..4095) + 3x transpose (4096..15359) --
__global__ __launch_bounds__(256)
void prep_kernel(const float* __restrict__ x, const float* __restrict__ ln1_s,
                 const float* __restrict__ ln1_b, __bf16* __restrict__ h1,
                 const float* __restrict__ w_qkv, __bf16* __restrict__ o_qkv,
                 const float* __restrict__ w_fc,  __bf16* __restrict__ o_fc,
                 const float* __restrict__ w_pj,  __bf16* __restrict__ o_pj) {
    __shared__ float tile[32][33];
    __shared__ float ssum[4], ssum2[4];
    int bid = blockIdx.x;
    int tid = threadIdx.x;
    if (bid < 4096) {
        ln_row_f4(x, ln1_s, ln1_b, h1, bid, ssum, ssum2);
        return;
    }
    int b2 = bid - 4096;
    const float* in; __bf16* out; int R, C, bx, by;
    if (b2 < 3072)       { in = w_qkv; out = o_qkv; R = 1024; C = 3072;
                           bx = b2 % 96;  by = b2 / 96;  }
    else if (b2 < 7168)  { in = w_fc;  out = o_fc;  R = 1024; C = 4096;
                           int r = b2 - 3072; bx = r % 128; by = r / 128; }
    else                 { in = w_pj;  out = o_pj;  R = 4096; C = 1024;
                           int r = b2 - 7168; bx = r % 32;  by = r / 32;  }
    int bc = bx * 32, br = by * 32;
    int tx = tid & 31, ty = tid >> 5;
    for (int i = 0; i < 32; i += 8)
        tile[ty + i][tx] = in[(size_t)(br + ty + i) * C + bc + tx];
    __syncthreads();
    for (int i = 0; i < 32; i += 8) {
        int c = bc + ty + i, r = br + tx;
        out[(size_t)c * R + r] = (__bf16)tile[tx][ty + i];
    }
}

// ---------------- layernorm (standalone, for LN2) --------------------------
__global__ __launch_bounds__(256)
void ln_kernel(const float* __restrict__ in, const float* __restrict__ sc,
               const float* __restrict__ sh, __bf16* __restrict__ out) {
    __shared__ float ssum[4], ssum2[4];
    ln_row_f4(in, sc, sh, out, blockIdx.x, ssum, ssum2);
}

// ---------------- bf16 MFMA GEMM, BM=BN=256 BK=64, 4-phase counted-vmcnt ---
// Per K-step t (buf c=t&1): tile t+1 staged into buf c^1 as 8 chunks spread
// 2/phase. Certification (vmcnt -> barrier, cross-wave safe):
//   ph4 of t-1: vmcnt(2) -> tile t's c0..c5 (a0 chunks + all B) landed.
//   ph2 of t:   vmcnt(4) -> tile t's c6,c7 (a1 chunks) landed (ph3 reads a1).
// Fresh-buffer ds_reads always issue after the certifying barrier. Waits are
// never 0 mid-loop (last iteration peels to vmcnt(0)).
__global__ __launch_bounds__(512)
void gemm256(const __bf16* __restrict__ A, const __bf16* __restrict__ Bt,
             const float* __restrict__ bias, const float* __restrict__ res,
             float* __restrict__ outF, __bf16* __restrict__ outB,
             int M, int N, int lda, int KL, int relu, int gx, int gz) {
    __shared__ __align__(16) __bf16 sA[2][256][64];
    __shared__ __align__(16) __bf16 sB[2][256][64];
    const int BUFE = 256 * 64;
    int tid  = threadIdx.x;
    int lane = tid & 63, wave = tid >> 6;
    int quad = lane >> 4, l16 = lane & 15;

    // XCD swizzle decode: pair p=(by*gz+bz) pinned to XCD p&7. grid%8==0.
    int i  = blockIdx.x;
    int c  = i & 7, m = i >> 3;
    int bx = m % gx;
    int p  = (m / gx) * 8 + c;
    int by = p / gz;
    int bz = p - by * gz;

    int bm = by * 256, bn = bx * 256;
    size_t k0 = (size_t)bz * KL;
    int wm = (wave >> 2) * 128, wn = (wave & 3) * 64;

    floatx4 acc[8][4] = {};

    int srow  = tid >> 3;
    int sslot = (tid & 7) ^ (srow & 7);
    const __bf16* gA = A  + (size_t)(bm + srow) * lda + k0 + sslot * 8;
    const __bf16* gB = Bt + (size_t)(bn + srow) * lda + k0 + sslot * 8;
    __bf16* lA = &sA[0][0][0] + wave * 512;
    __bf16* lB = &sB[0][0][0] + wave * 512;
    const size_t rstep = (size_t)64 * lda;

    // prologue: tile 0 all 8 chunks, drain once
    GLOBAL_LOAD_LDS16(gA,             lA);
    GLOBAL_LOAD_LDS16(gA + 2 * rstep, lA + 8192);
    GLOBAL_LOAD_LDS16(gB,             lB);
    GLOBAL_LOAD_LDS16(gB + rstep,     lB + 4096);
    GLOBAL_LOAD_LDS16(gB + 2 * rstep, lB + 8192);
    GLOBAL_LOAD_LDS16(gB + 3 * rstep, lB + 12288);
    GLOBAL_LOAD_LDS16(gA + rstep,     lA + 4096);
    GLOBAL_LOAD_LDS16(gA + 3 * rstep, lA + 12288);
    asm volatile("s_waitcnt vmcnt(0)" ::: "memory");
    __builtin_amdgcn_s_barrier();

    int xs0  = ((quad) ^ (l16 & 7)) * 8;
    int xs1  = ((4 + quad) ^ (l16 & 7)) * 8;
    int aoff = (wm + l16) * 64;
    int boff = (wn + l16) * 64;

#define PH_IN() do { __builtin_amdgcn_s_barrier(); \
    asm volatile("s_waitcnt lgkmcnt(0)" ::: "memory"); \
    __builtin_amdgcn_sched_barrier(0); } while (0)

    const int nt = KL / 64;
    for (int t = 0; t < nt; ++t) {
        const int cur  = t & 1;
        const int nb   = cur ^ 1;
        const bool more = (t + 1 < nt);
        const size_t ko = (size_t)(t + 1) * 64;
        const __bf16* sAc = &sA[0][0][0] + cur * BUFE;
        const __bf16* sBc = &sB[0][0][0] + cur * BUFE;

        bf16x8 a0[4][2], a1[4][2], b0[2][2], b1[2][2];

        // ---- phase 1: ds a0(8)+b0(4); stage c0,c1; MFMA a0xb0
        #pragma unroll
        for (int mi = 0; mi < 4; ++mi) {
            a0[mi][0] = *(const bf16x8*)(sAc + aoff + mi * 1024 + xs0);
            a0[mi][1] = *(const bf16x8*)(sAc + aoff + mi * 1024 + xs1);
        }
        #pragma unroll
        for (int nj = 0; nj < 2; ++nj) {
            b0[nj][0] = *(const bf16x8*)(sBc + boff + nj * 1024 + xs0);
            b0[nj][1] = *(const bf16x8*)(sBc + boff + nj * 1024 + xs1);
        }
        if (more) {
            GLOBAL_LOAD_LDS16(gA + ko,             lA + nb * BUFE);
            GLOBAL_LOAD_LDS16(gA + ko + 2 * rstep, lA + nb * BUFE + 8192);
        }
        PH_IN();
        __builtin_amdgcn_s_setprio(1);
        #pragma unroll
        for (int ks = 0; ks < 2; ++ks)
            #pragma unroll
            for (int mi = 0; mi < 4; ++mi)
                #pragma unroll
                for (int nj = 0; nj < 2; ++nj)
                    acc[mi][nj] = __builtin_amdgcn_mfma_f32_16x16x32_bf16(
                        a0[mi][ks], b0[nj][ks], acc[mi][nj], 0, 0, 0);
        __builtin_amdgcn_s_setprio(0);
        __builtin_amdgcn_s_barrier();

        // ---- phase 2: ds b1(4); stage c2,c3; vmcnt(4|0); MFMA a0xb1
        #pragma unroll
        for (int nj = 0; nj < 2; ++nj) {
            b1[nj][0] = *(const bf16x8*)(sBc + boff + (2 + nj) * 1024 + xs0);
            b1[nj][1] = *(const bf16x8*)(sBc + boff + (2 + nj) * 1024 + xs1);
        }
        if (more) {
            GLOBAL_LOAD_LDS16(gB + ko,         lB + nb * BUFE);
            GLOBAL_LOAD_LDS16(gB + ko + rstep, lB + nb * BUFE + 4096);
            asm volatile("s_waitcnt vmcnt(4)" ::: "memory");
        } else {
            asm volatile("s_waitcnt vmcnt(0)" ::: "memory");
        }
        PH_IN();
        __builtin_amdgcn_s_setprio(1);
        #pragma unroll
        for (int ks = 0; ks < 2; ++ks)
            #pragma unroll
            for (int mi = 0; mi < 4; ++mi)
                #pragma unroll
                for (int nj = 0; nj < 2; ++nj)
                    acc[mi][2 + nj] = __builtin_amdgcn_mfma_f32_16x16x32_bf16(
                        a0[mi][ks], b1[nj][ks], acc[mi][2 + nj], 0, 0, 0);
        __builtin_amdgcn_s_setprio(0);
        __builtin_amdgcn_s_barrier();

        // ---- phase 3: ds a1(8); stage c4,c5; MFMA a1xb1
        #pragma unroll
        for (int mi = 0; mi < 4; ++mi) {
            a1[mi][0] = *(const bf16x8*)(sAc + aoff + (4 + mi) * 1024 + xs0);
            a1[mi][1] = *(const bf16x8*)(sAc + aoff + (4 + mi) * 1024 + xs1);
        }
        if (more) {
            GLOBAL_LOAD_LDS16(gB + ko + 2 * rstep, lB + nb * BUFE + 8192);
            GLOBAL_LOAD_LDS16(gB + ko + 3 * rstep, lB + nb * BUFE + 12288);
        }
        PH_IN();
        __builtin_amdgcn_s_setprio(1);
        #pragma unroll
        for (int ks = 0; ks < 2; ++ks)
            #pragma unroll
            for (int mi = 0; mi < 4; ++mi)
                #pragma unroll
                for (int nj = 0; nj < 2; ++nj)
                    acc[4 + mi][2 + nj] = __builtin_amdgcn_mfma_f32_16x16x32_bf16(
                        a1[mi][ks], b1[nj][ks], acc[4 + mi][2 + nj], 0, 0, 0);
        __builtin_amdgcn_s_setprio(0);
        __builtin_amdgcn_s_barrier();

        // ---- phase 4: stage c6,c7; vmcnt(2|0); barrier; MFMA a1xb0
        if (more) {
            GLOBAL_LOAD_LDS16(gA + ko + rstep,     lA + nb * BUFE + 4096);
            GLOBAL_LOAD_LDS16(gA + ko + 3 * rstep, lA + nb * BUFE + 12288);
            asm volatile("s_waitcnt vmcnt(2)" ::: "memory");
        } else {
            asm volatile("s_waitcnt vmcnt(0)" ::: "memory");
        }
        __builtin_amdgcn_s_barrier();
        asm volatile("" ::: "memory");
        __builtin_amdgcn_s_setprio(1);
        #pragma unroll
        for (int ks = 0; ks < 2; ++ks)
            #pragma unroll
            for (int mi = 0; mi < 4; ++mi)
                #pragma unroll
                for (int nj = 0; nj < 2; ++nj)
                    acc[4 + mi][nj] = __builtin_amdgcn_mfma_f32_16x16x32_bf16(
                        a1[mi][ks], b0[nj][ks], acc[4 + mi][nj], 0, 0, 0);
        __builtin_amdgcn_s_setprio(0);
    }
#undef PH_IN

    if (bias) {
        #pragma unroll
        for (int mi = 0; mi < 8; ++mi) {
            int row0 = bm + wm + mi * 16 + quad * 4;
            #pragma unroll
            for (int nj = 0; nj < 4; ++nj) {
                int col = bn + wn + nj * 16 + l16;
                float bv = bias[col];
                #pragma unroll
                for (int r = 0; r < 4; ++r) {
                    size_t idx = (size_t)(row0 + r) * N + col;
                    float cc = acc[mi][nj][r] + bv;
                    if (relu) cc = fmaxf(cc, 0.f);
                    if (res)  cc += res[idx];
                    if (outF) outF[idx] = cc;
                    if (outB) outB[idx] = (__bf16)cc;
                }
            }
        }
    } else {
        __bf16* po = outB + (size_t)bz * M * N;
        #pragma unroll
        for (int mi = 0; mi < 8; ++mi) {
            int row0 = bm + wm + mi * 16 + quad * 4;
            #pragma unroll
            for (int nj = 0; nj < 4; ++nj) {
                int col = bn + wn + nj * 16 + l16;
                #pragma unroll
                for (int r = 0; r < 4; ++r)
                    po[(size_t)(row0 + r) * N + col] = (__bf16)acc[mi][nj][r];
            }
        }
    }
}

// ---------------- split-K reduce: out = x2 + bias + sum of 4 bf16 partials -
__global__ __launch_bounds__(256)
void reduce_proj(const __bf16* __restrict__ pbuf, const float* __restrict__ x2,
                 const float* __restrict__ bias, float* __restrict__ out) {
    const size_t MN = (size_t)4096 * 1024;
    size_t i = (size_t)blockIdx.x * 256 + threadIdx.x;   // float4 index
    float4 r = ((const float4*)x2)[i];
    float4 bb = ((const float4*)bias)[i & 255];
    float acc0 = r.x + bb.x, acc1 = r.y + bb.y;
    float acc2 = r.z + bb.z, acc3 = r.w + bb.w;
    for (int k = 0; k < 4; k++) {
        bf16x4 pv = *(const bf16x4*)&pbuf[k * MN + i * 4];
        acc0 += (float)pv[0]; acc1 += (float)pv[1];
        acc2 += (float)pv[2]; acc3 += (float)pv[3];
    }
    float4 o = {acc0, acc1, acc2, acc3};
    ((float4*)out)[i] = o;
}

// ---------------- bf16 MFMA GEMM (BM=128, BN=64) — ws-fallback only --------
__global__ __launch_bounds__(256)
void gemm_bt_n64(const __bf16* __restrict__ A, const __bf16* __restrict__ Bt,
                 const float* __restrict__ bias, const float* __restrict__ res,
                 float* __restrict__ outF, __bf16* __restrict__ outB,
                 int M, int N, int K, int relu) {
    __shared__ __align__(16) __bf16 sA[128][40];
    __shared__ __align__(16) __bf16 sB[64][40];
    int tid  = threadIdx.x;
    int lane = tid & 63, wave = tid >> 6;
    int quad = lane >> 4, l16 = lane & 15;
    int bm = blockIdx.y * 128, bn = blockIdx.x * 64;
    int wm = (wave & 1) * 64, wn = (wave >> 1) * 32;
    floatx4 acc[4][2] = {};

    int srow = tid >> 2;
    int scol = (tid & 3) * 8;
    const __bf16* gA = &A[(size_t)(bm + srow) * K + scol];
    const __bf16* gB = &Bt[(size_t)(bn + srow) * K + scol];

    uint4 ra0 = *(const uint4*)gA;
    uint4 ra1 = *(const uint4*)(gA + (size_t)64 * K);
    uint4 rb0 = *(const uint4*)gB;

    for (int kk = 0; kk < K; kk += 32) {
        __syncthreads();
        *(uint4*)&sA[srow][scol]      = ra0;
        *(uint4*)&sA[srow + 64][scol] = ra1;
        *(uint4*)&sB[srow][scol]      = rb0;
        __syncthreads();
        {
            int kn = (kk + 32 < K) ? kk + 32 : kk;
            ra0 = *(const uint4*)(gA + kn);
            ra1 = *(const uint4*)(gA + kn + (size_t)64 * K);
            rb0 = *(const uint4*)(gB + kn);
        }
        bf16x8 af[4], bfr[2];
        for (int i = 0; i < 4; i++)
            af[i] = *(const bf16x8*)&sA[wm + i * 16 + l16][quad * 8];
        for (int j = 0; j < 2; j++)
            bfr[j] = *(const bf16x8*)&sB[wn + j * 16 + l16][quad * 8];
        for (int i = 0; i < 4; i++)
            for (int j = 0; j < 2; j++)
                acc[i][j] = __builtin_amdgcn_mfma_f32_16x16x32_bf16(
                    af[i], bfr[j], acc[i][j], 0, 0, 0);
    }

    for (int i = 0; i < 4; i++) {
        int row0 = bm + wm + i * 16 + quad * 4;
        for (int j = 0; j < 2; j++) {
            int col = bn + wn + j * 16 + l16;
            float bv = bias[col];
            for (int r = 0; r < 4; r++) {
                size_t idx = (size_t)(row0 + r) * N + col;
                float c = acc[i][j][r] + bv;
                if (relu) c = fmaxf(c, 0.f);
                if (res)  c += res[idx];
                if (outF) outF[idx] = c;
                if (outB) outB[idx] = (__bf16)c;
            }
        }
    }
}

// ---------------- flash attention: CU-balanced complementary pairs --------
// grid 512: i -> XCD c=i&7, m=i>>3. Dispatch model: XCD x receives m=j in
// order; CU k hosts j=k and j=k+32. pair=(j<8)?j:23-j -> CU runs pairs
// (q, 15-q): 49 iterations on EVERY CU. Waves 0-3 heavy qt_h=31-pair,
// waves 4-7 light=pair (16 rows/wave); light group skips past-diagonal
// tiles (wave-uniform, barriers outside). Softmax fixed-max exp2,
// wave-private sP. T5 setprio(1) around QK/PV MFMA clusters.
__global__ __launch_bounds__(512)
void attn_kernel(const __bf16* __restrict__ qkv, const float* __restrict__ x,
                 float* __restrict__ x2) {
    __shared__ __align__(16) __bf16 sK[2][64][72];
    __shared__ __align__(16) __bf16 sVt[2][64][72];
    __shared__ __align__(16) __bf16 sP[8][16][72];
    const int tid  = threadIdx.x;
    const int lane = tid & 63, wave = tid >> 6;
    const int quad = lane >> 4, l16 = lane & 15;

    int i = blockIdx.x;
    int c = i & 7, m = i >> 3;
    const int bh   = (m & 3) * 8 + c;          // 0..31, XCD-pinned
    const int j_   = m >> 2;                   // 0..15 dispatch-order index
    const int pair = (j_ < 8) ? j_ : 23 - j_;  // CU-balanced bijection
    const int qt_h = 31 - pair;                // heavy q-tile, 16..31
    const int h    = bh & (NH - 1);
    const int b    = bh >> 4;
    const size_t rowbase = (size_t)b * T_LEN;

    const int g  = wave >> 2;                  // 0 = heavy group, 1 = light
    const int wg = wave & 3;
    const int qt = g ? pair : qt_h;            // this group's q-tile
    const int qrow = qt * 64 + wg * 16;        // this wave's 16 q rows
    const int dt   = qt;                       // group's diagonal K-tile

    const float kQScale = 0.125f * 1.44269504088896f;
    bf16x8 ones;
    for (int j = 0; j < 8; j++) ones[j] = (__bf16)1.0f;

    // staging: 512 threads cover 64 keys x 8 chunks, one uint4 each
    const int key0 = tid >> 3, m8 = tid & 7;
    const __bf16* kp0 = qkv + (rowbase + key0) * 3072 + h * HD + m8 * 8 + 1024;
    const int pc0 = ((key0 >> 3) ^ m8) * 8 + (key0 & 7);

    bf16x8 qf[2];
    for (int ks = 0; ks < 2; ks++) {
        bf16x8 raw = *(const bf16x8*)&qkv[(rowbase + qrow + l16) * 3072
                                          + h * HD + ks * 32 + quad * 8];
        for (int j = 0; j < 8; j++)
            qf[ks][j] = (__bf16)((float)raw[j] * kQScale);
    }

    floatx4 o[4] = {}, ol = {};

    const int ntiles = qt_h + 1;               // 17..32
    const size_t TSTEP = (size_t)64 * 3072;

    // prologue: tile 0 -> regs -> buf0 ; tile 1 -> regs ; barrier
    uint4 kr0 = *(const uint4*)kp0;
    uint4 vr0 = *(const uint4*)(kp0 + 1024);
    {
        *(uint4*)&sK[0][key0][m8 * 8] = kr0;
        bf16x8 v0 = *(bf16x8*)&vr0;
        for (int j = 0; j < 8; j++) sVt[0][m8 * 8 + j][pc0] = v0[j];
    }
    kr0 = *(const uint4*)(kp0 + TSTEP);            // ntiles >= 17 always
    vr0 = *(const uint4*)(kp0 + TSTEP + 1024);
    __syncthreads();

    for (int kt = 0; kt < ntiles; kt++) {
        const int cur = kt & 1, nxt = cur ^ 1;
        if (kt + 1 < ntiles) {
            *(uint4*)&sK[nxt][key0][m8 * 8] = kr0;
            bf16x8 v0 = *(bf16x8*)&vr0;
            for (int j = 0; j < 8; j++) sVt[nxt][m8 * 8 + j][pc0] = v0[j];
            size_t offn = (size_t)((kt + 2 < ntiles) ? kt + 2 : kt + 1) * TSTEP;
            kr0 = *(const uint4*)(kp0 + offn);
            vr0 = *(const uint4*)(kp0 + offn + 1024);
        }

        if (kt <= dt) {
            // S = Q K^T (exp2 domain) from buf[cur]
            floatx4 s_acc[4] = {};
            __builtin_amdgcn_s_setprio(1);
            for (int jt = 0; jt < 4; jt++)
                for (int ks = 0; ks < 2; ks++) {
                    bf16x8 kf = *(const bf16x8*)&sK[cur][jt * 16 + l16]
                                                  [ks * 32 + quad * 8];
                    s_acc[jt] = __builtin_amdgcn_mfma_f32_16x16x32_bf16(
                        qf[ks], kf, s_acc[jt], 0, 0, 0);
                }
            __builtin_amdgcn_s_setprio(0);

            // P = exp2(min(s,30)); mask only on this group's diagonal tile.
            if (kt == dt) {
                const int tq0 = qrow + quad * 4;
                const int k0 = kt * 64;
                for (int jt = 0; jt < 4; jt++) {
                    int key = k0 + jt * 16 + l16;
                    for (int r = 0; r < 4; r++) {
                        float sv = (key <= tq0 + r) ? s_acc[jt][r] : -1e30f;
                        float pv = __builtin_amdgcn_exp2f(fminf(sv, 30.f));
                        sP[wave][quad * 4 + r][jt * 16 + l16] = (__bf16)pv;
                    }
                }
            } else {
                for (int jt = 0; jt < 4; jt++)
                    for (int r = 0; r < 4; r++) {
                        float pv = __builtin_amdgcn_exp2f(fminf(s_acc[jt][r], 30.f));
                        sP[wave][quad * 4 + r][jt * 16 + l16] = (__bf16)pv;
                    }
            }
            // sP wave-private: lgkmcnt ordering suffices, no barrier.

            for (int kp = 0; kp < 2; kp++) {
                bf16x8 pf = *(const bf16x8*)&sP[wave][l16][kp * 32 + quad * 8];
                __builtin_amdgcn_s_setprio(1);
                ol = __builtin_amdgcn_mfma_f32_16x16x32_bf16(pf, ones, ol, 0, 0, 0);
                for (int jt2 = 0; jt2 < 4; jt2++) {
                    int d = jt2 * 16 + l16;
                    int pg = (kp * 4 + quad) ^ (d >> 3);
                    bf16x8 vf = *(const bf16x8*)&sVt[cur][d][pg * 8];
                    o[jt2] = __builtin_amdgcn_mfma_f32_16x16x32_bf16(
                        pf, vf, o[jt2], 0, 0, 0);
                }
                __builtin_amdgcn_s_setprio(0);
            }
        }
        __syncthreads();   // all waves done reading cur & writing nxt
    }

    float inv[4];
    for (int r = 0; r < 4; r++) inv[r] = __builtin_amdgcn_rcpf(ol[r]);
    for (int jt2 = 0; jt2 < 4; jt2++) {
        for (int r = 0; r < 4; r++) {
            int tq  = qrow + quad * 4 + r;
            int col = h * HD + jt2 * 16 + l16;
            size_t gi = (rowbase + tq) * EMB + col;
            x2[gi] = x[gi] + o[jt2][r] * inv[r];
        }
    }
}

// ---------------------------------------------------------------------------
extern "C" void kernel_launch(void* const* d_in, const int* in_sizes, int n_in,
                              void* d_out, int out_size, void* d_ws, size_t ws_size,
                              hipStream_t stream) {
    const float* x      = (const float*)d_in[0];
    const float* ln1_s  = (const float*)d_in[1];
    const float* ln1_b  = (const float*)d_in[2];
    const float* w_qkv  = (const float*)d_in[3];
    const float* b_qkv  = (const float*)d_in[4];
    const float* ln2_s  = (const float*)d_in[5];
    const float* ln2_b  = (const float*)d_in[6];
    const float* w_fc   = (const float*)d_in[7];
    const float* b_fc   = (const float*)d_in[8];
    const float* w_proj = (const float*)d_in[9];
    const float* b_proj = (const float*)d_in[10];
    float* out = (float*)d_out;

    const int M = 2 * T_LEN;  // 4096 rows
    char* ws = (char*)d_ws;
    size_t off = 0;
    auto alloc = [&](size_t bytes) {
        void* p = ws + off; off += (bytes + 255) & ~(size_t)255; return p;
    };
    // alive through proj:
    __bf16* wpj_t  = (__bf16*)alloc((size_t)1024 * 4096 * 2);
    float*  x2     = (float*) alloc((size_t)M * 1024 * 4);
    __bf16* hfc    = (__bf16*)alloc((size_t)M * 4096 * 2);
    size_t mark = off;                    // dead-by-proj region starts here
    __bf16* wqkv_t = (__bf16*)alloc((size_t)3072 * 1024 * 2);
    __bf16* wfc_t  = (__bf16*)alloc((size_t)4096 * 1024 * 2);
    __bf16* h1     = (__bf16*)alloc((size_t)M * 1024 * 2);
    __bf16* h2     = (__bf16*)alloc((size_t)M * 1024 * 2);
    __bf16* qkvb   = (__bf16*)alloc((size_t)M * 3072 * 2);
    // split-K bf16 partials overlay the dead region.
    __bf16* pbuf = (__bf16*)(ws + mark);
    size_t need = mark + (size_t)4 * M * 1024 * 2;
    bool can_split = ws_size >= need;

    // LN1 + 3x weight transpose fused (independent work, one launch)
    prep_kernel<<<15360, 256, 0, stream>>>(x, ln1_s, ln1_b, h1,
                                           w_qkv, wqkv_t, w_fc, wfc_t,
                                           w_proj, wpj_t);

    // qkv = LN1(x) @ w_qkv + b_qkv -> bf16 ; grid 16x12 flattened (192)
    gemm256<<<192, 512, 0, stream>>>(
        h1, wqkv_t, b_qkv, nullptr, nullptr, qkvb, M, 3072, 1024, 1024, 0,
        12, 1);

    attn_kernel<<<512, 512, 0, stream>>>(qkvb, x, x2);

    ln_kernel<<<M, 256, 0, stream>>>(x2, ln2_s, ln2_b, h2);

    // hfc = relu(h2 @ w_fc + b_fc) -> bf16 ; grid 16x16 flattened (256)
    gemm256<<<256, 512, 0, stream>>>(
        h2, wfc_t, b_fc, nullptr, nullptr, hfc, M, 4096, 1024, 1024, 1,
        16, 1);

    if (can_split) {
        // proj partials: 4 K-chunks of 1024, grid 16x4x4 flattened (256)
        gemm256<<<256, 512, 0, stream>>>(
            hfc, wpj_t, nullptr, nullptr, nullptr, pbuf, M, 1024, 4096, 1024, 0,
            4, 4);
        reduce_proj<<<(M * 1024 / 4) / 256, 256, 0, stream>>>(
            pbuf, x2, b_proj, out);
    } else {
        gemm_bt_n64<<<dim3(1024 / 64, M / 128), 256, 0, stream>>>(
            hfc, wpj_t, b_proj, x2, out, nullptr, M, 1024, 4096, 0);
    }
}

// Round 17
// 285.027 us; speedup vs baseline: 1.3149x; 1.0038x over previous
//
#include <hip/hip_runtime.h>
#include <hip/hip_bf16.h>

// ---------------------------------------------------------------------------
// Transformer block: x + attn(LN1(x)) ; then x2 + proj(relu(fc(LN2(x2))))
// B=2, T=2048, C=1024, H=16, hd=64, MLP hidden 4096. All GEMMs bf16 MFMA.
// R27 = R25/R22 (verified best, 286.1us; R16 round was an infra failure).
//   WINS: gemm256 4-phase counted-vmcnt (R22, -8us); attn CU-balanced
//   complementary pairs + T5 setprio (R21, -4us); prep fusion + f4 LN (R22).
//   CLOSED LINES (counter evidence): bank conflicts (R13/R16: timing-
//   insensitive); attn LDS traffic (R16: -26% regression); per-phase double
//   barriers at 1 block/CU (R17: serializes); 128^2/BK32 tiling at K=1024
//   (R19: 520 TF < 741); cross-tile QK lookahead (R20: VALU overhead);
//   split-K finisher fusion (R23 races cross-XCD; R24 same-XCD breaks
//   K-chunk locality, FETCH 3.4x); cooperative LN2 (R23).
//   Plateau: attn latency-bound at 2-blocks/CU cap; gemms at K=1024
//   schedule ceiling; ~60us launch gaps with fusion mechanisms disproven.
// ---------------------------------------------------------------------------

typedef __bf16  bf16x8  __attribute__((ext_vector_type(8)));
typedef __bf16  bf16x4  __attribute__((ext_vector_type(4)));
typedef float   floatx4 __attribute__((ext_vector_type(4)));

#define T_LEN 2048
#define EMB   1024
#define NH    16
#define HD    64
#define HID   4096

#define GLOBAL_LOAD_LDS16(gp, lp) \
    __builtin_amdgcn_global_load_lds( \
        (const __attribute__((address_space(1))) void*)(gp), \
        (__attribute__((address_space(3))) void*)(lp), 16, 0, 0)

// ---------------- LN row helper: float4 loads, 256 threads -----------------
__device__ __forceinline__ void ln_row_f4(const float* __restrict__ in,
        const float* __restrict__ sc, const float* __restrict__ sh,
        __bf16* __restrict__ out, int row, float* ssum, float* ssum2) {
    int tid = threadIdx.x;
    int lane = tid & 63, wave = tid >> 6;
    float4 v = ((const float4*)(in + (size_t)row * EMB))[tid];
    float s  = v.x + v.y + v.z + v.w;
    float s2 = v.x * v.x + v.y * v.y + v.z * v.z + v.w * v.w;
    for (int m = 1; m < 64; m <<= 1) {
        s  += __shfl_xor(s, m);
        s2 += __shfl_xor(s2, m);
    }
    if (lane == 0) { ssum[wave] = s; ssum2[wave] = s2; }
    __syncthreads();
    float tot  = ssum[0] + ssum[1] + ssum[2] + ssum[3];
    float tot2 = ssum2[0] + ssum2[1] + ssum2[2] + ssum2[3];
    float mean = tot * (1.f / EMB);
    float rstd = rsqrtf(tot2 * (1.f / EMB) - mean * mean + 1e-5f);
    float4 sv = ((const float4*)sc)[tid];
    float4 hv = ((const float4*)sh)[tid];
    bf16x4 o;
    o[0] = (__bf16)((v.x - mean) * rstd * sv.x + hv.x);
    o[1] = (__bf16)((v.y - mean) * rstd * sv.y + hv.y);
    o[2] = (__bf16)((v.z - mean) * rstd * sv.z + hv.z);
    o[3] = (__bf16)((v.w - mean) * rstd * sv.w + hv.w);
    *(bf16x4*)(out + (size_t)row * EMB + tid * 4) = o;
}

// ---------------- prep: LN1 (blocks 0..4095) + 3x transpose (4096..15359) --
__global__ __launch_bounds__(256)
void prep_kernel(const float* __restrict__ x, const float* __restrict__ ln1_s,
                 const float* __restrict__ ln1_b, __bf16* __restrict__ h1,
                 const float* __restrict__ w_qkv, __bf16* __restrict__ o_qkv,
                 const float* __restrict__ w_fc,  __bf16* __restrict__ o_fc,
                 const float* __restrict__ w_pj,  __bf16* __restrict__ o_pj) {
    __shared__ float tile[32][33];
    __shared__ float ssum[4], ssum2[4];
    int bid = blockIdx.x;
    int tid = threadIdx.x;
    if (bid < 4096) {
        ln_row_f4(x, ln1_s, ln1_b, h1, bid, ssum, ssum2);
        return;
    }
    int b2 = bid - 4096;
    const float* in; __bf16* out; int R, C, bx, by;
    if (b2 < 3072)       { in = w_qkv; out = o_qkv; R = 1024; C = 3072;
                           bx = b2 % 96;  by = b2 / 96;  }
    else if (b2 < 7168)  { in = w_fc;  out = o_fc;  R = 1024; C = 4096;
                           int r = b2 - 3072; bx = r % 128; by = r / 128; }
    else                 { in = w_pj;  out = o_pj;  R = 4096; C = 1024;
                           int r = b2 - 7168; bx = r % 32;  by = r / 32;  }
    int bc = bx * 32, br = by * 32;
    int tx = tid & 31, ty = tid >> 5;
    for (int i = 0; i < 32; i += 8)
        tile[ty + i][tx] = in[(size_t)(br + ty + i) * C + bc + tx];
    __syncthreads();
    for (int i = 0; i < 32; i += 8) {
        int c = bc + ty + i, r = br + tx;
        out[(size_t)c * R + r] = (__bf16)tile[tx][ty + i];
    }
}

// ---------------- layernorm (standalone, for LN2) --------------------------
__global__ __launch_bounds__(256)
void ln_kernel(const float* __restrict__ in, const float* __restrict__ sc,
               const float* __restrict__ sh, __bf16* __restrict__ out) {
    __shared__ float ssum[4], ssum2[4];
    ln_row_f4(in, sc, sh, out, blockIdx.x, ssum, ssum2);
}

// ---------------- bf16 MFMA GEMM, BM=BN=256 BK=64, 4-phase counted-vmcnt ---
// Per K-step t (buf c=t&1): tile t+1 staged into buf c^1 as 8 chunks spread
// 2/phase. Certification (vmcnt -> barrier, cross-wave safe):
//   ph4 of t-1: vmcnt(2) -> tile t's c0..c5 (a0 chunks + all B) landed.
//   ph2 of t:   vmcnt(4) -> tile t's c6,c7 (a1 chunks) landed (ph3 reads a1).
// Fresh-buffer ds_reads always issue after the certifying barrier. Waits are
// never 0 mid-loop (last iteration peels to vmcnt(0)).
__global__ __launch_bounds__(512)
void gemm256(const __bf16* __restrict__ A, const __bf16* __restrict__ Bt,
             const float* __restrict__ bias, const float* __restrict__ res,
             float* __restrict__ outF, __bf16* __restrict__ outB,
             int M, int N, int lda, int KL, int relu, int gx, int gz) {
    __shared__ __align__(16) __bf16 sA[2][256][64];
    __shared__ __align__(16) __bf16 sB[2][256][64];
    const int BUFE = 256 * 64;
    int tid  = threadIdx.x;
    int lane = tid & 63, wave = tid >> 6;
    int quad = lane >> 4, l16 = lane & 15;

    // XCD swizzle decode: pair p=(by*gz+bz) pinned to XCD p&7. grid%8==0.
    int i  = blockIdx.x;
    int c  = i & 7, m = i >> 3;
    int bx = m % gx;
    int p  = (m / gx) * 8 + c;
    int by = p / gz;
    int bz = p - by * gz;

    int bm = by * 256, bn = bx * 256;
    size_t k0 = (size_t)bz * KL;
    int wm = (wave >> 2) * 128, wn = (wave & 3) * 64;

    floatx4 acc[8][4] = {};

    int srow  = tid >> 3;
    int sslot = (tid & 7) ^ (srow & 7);
    const __bf16* gA = A  + (size_t)(bm + srow) * lda + k0 + sslot * 8;
    const __bf16* gB = Bt + (size_t)(bn + srow) * lda + k0 + sslot * 8;
    __bf16* lA = &sA[0][0][0] + wave * 512;
    __bf16* lB = &sB[0][0][0] + wave * 512;
    const size_t rstep = (size_t)64 * lda;

    // prologue: tile 0 all 8 chunks, drain once
    GLOBAL_LOAD_LDS16(gA,             lA);
    GLOBAL_LOAD_LDS16(gA + 2 * rstep, lA + 8192);
    GLOBAL_LOAD_LDS16(gB,             lB);
    GLOBAL_LOAD_LDS16(gB + rstep,     lB + 4096);
    GLOBAL_LOAD_LDS16(gB + 2 * rstep, lB + 8192);
    GLOBAL_LOAD_LDS16(gB + 3 * rstep, lB + 12288);
    GLOBAL_LOAD_LDS16(gA + rstep,     lA + 4096);
    GLOBAL_LOAD_LDS16(gA + 3 * rstep, lA + 12288);
    asm volatile("s_waitcnt vmcnt(0)" ::: "memory");
    __builtin_amdgcn_s_barrier();

    int xs0  = ((quad) ^ (l16 & 7)) * 8;
    int xs1  = ((4 + quad) ^ (l16 & 7)) * 8;
    int aoff = (wm + l16) * 64;
    int boff = (wn + l16) * 64;

#define PH_IN() do { __builtin_amdgcn_s_barrier(); \
    asm volatile("s_waitcnt lgkmcnt(0)" ::: "memory"); \
    __builtin_amdgcn_sched_barrier(0); } while (0)

    const int nt = KL / 64;
    for (int t = 0; t < nt; ++t) {
        const int cur  = t & 1;
        const int nb   = cur ^ 1;
        const bool more = (t + 1 < nt);
        const size_t ko = (size_t)(t + 1) * 64;
        const __bf16* sAc = &sA[0][0][0] + cur * BUFE;
        const __bf16* sBc = &sB[0][0][0] + cur * BUFE;

        bf16x8 a0[4][2], a1[4][2], b0[2][2], b1[2][2];

        // ---- phase 1: ds a0(8)+b0(4); stage c0,c1; MFMA a0xb0
        #pragma unroll
        for (int mi = 0; mi < 4; ++mi) {
            a0[mi][0] = *(const bf16x8*)(sAc + aoff + mi * 1024 + xs0);
            a0[mi][1] = *(const bf16x8*)(sAc + aoff + mi * 1024 + xs1);
        }
        #pragma unroll
        for (int nj = 0; nj < 2; ++nj) {
            b0[nj][0] = *(const bf16x8*)(sBc + boff + nj * 1024 + xs0);
            b0[nj][1] = *(const bf16x8*)(sBc + boff + nj * 1024 + xs1);
        }
        if (more) {
            GLOBAL_LOAD_LDS16(gA + ko,             lA + nb * BUFE);
            GLOBAL_LOAD_LDS16(gA + ko + 2 * rstep, lA + nb * BUFE + 8192);
        }
        PH_IN();
        __builtin_amdgcn_s_setprio(1);
        #pragma unroll
        for (int ks = 0; ks < 2; ++ks)
            #pragma unroll
            for (int mi = 0; mi < 4; ++mi)
                #pragma unroll
                for (int nj = 0; nj < 2; ++nj)
                    acc[mi][nj] = __builtin_amdgcn_mfma_f32_16x16x32_bf16(
                        a0[mi][ks], b0[nj][ks], acc[mi][nj], 0, 0, 0);
        __builtin_amdgcn_s_setprio(0);
        __builtin_amdgcn_s_barrier();

        // ---- phase 2: ds b1(4); stage c2,c3; vmcnt(4|0); MFMA a0xb1
        #pragma unroll
        for (int nj = 0; nj < 2; ++nj) {
            b1[nj][0] = *(const bf16x8*)(sBc + boff + (2 + nj) * 1024 + xs0);
            b1[nj][1] = *(const bf16x8*)(sBc + boff + (2 + nj) * 1024 + xs1);
        }
        if (more) {
            GLOBAL_LOAD_LDS16(gB + ko,         lB + nb * BUFE);
            GLOBAL_LOAD_LDS16(gB + ko + rstep, lB + nb * BUFE + 4096);
            asm volatile("s_waitcnt vmcnt(4)" ::: "memory");
        } else {
            asm volatile("s_waitcnt vmcnt(0)" ::: "memory");
        }
        PH_IN();
        __builtin_amdgcn_s_setprio(1);
        #pragma unroll
        for (int ks = 0; ks < 2; ++ks)
            #pragma unroll
            for (int mi = 0; mi < 4; ++mi)
                #pragma unroll
                for (int nj = 0; nj < 2; ++nj)
                    acc[mi][2 + nj] = __builtin_amdgcn_mfma_f32_16x16x32_bf16(
                        a0[mi][ks], b1[nj][ks], acc[mi][2 + nj], 0, 0, 0);
        __builtin_amdgcn_s_setprio(0);
        __builtin_amdgcn_s_barrier();

        // ---- phase 3: ds a1(8); stage c4,c5; MFMA a1xb1
        #pragma unroll
        for (int mi = 0; mi < 4; ++mi) {
            a1[mi][0] = *(const bf16x8*)(sAc + aoff + (4 + mi) * 1024 + xs0);
            a1[mi][1] = *(const bf16x8*)(sAc + aoff + (4 + mi) * 1024 + xs1);
        }
        if (more) {
            GLOBAL_LOAD_LDS16(gB + ko + 2 * rstep, lB + nb * BUFE + 8192);
            GLOBAL_LOAD_LDS16(gB + ko + 3 * rstep, lB + nb * BUFE + 12288);
        }
        PH_IN();
        __builtin_amdgcn_s_setprio(1);
        #pragma unroll
        for (int ks = 0; ks < 2; ++ks)
            #pragma unroll
            for (int mi = 0; mi < 4; ++mi)
                #pragma unroll
                for (int nj = 0; nj < 2; ++nj)
                    acc[4 + mi][2 + nj] = __builtin_amdgcn_mfma_f32_16x16x32_bf16(
                        a1[mi][ks], b1[nj][ks], acc[4 + mi][2 + nj], 0, 0, 0);
        __builtin_amdgcn_s_setprio(0);
        __builtin_amdgcn_s_barrier();

        // ---- phase 4: stage c6,c7; vmcnt(2|0); barrier; MFMA a1xb0
        if (more) {
            GLOBAL_LOAD_LDS16(gA + ko + rstep,     lA + nb * BUFE + 4096);
            GLOBAL_LOAD_LDS16(gA + ko + 3 * rstep, lA + nb * BUFE + 12288);
            asm volatile("s_waitcnt vmcnt(2)" ::: "memory");
        } else {
            asm volatile("s_waitcnt vmcnt(0)" ::: "memory");
        }
        __builtin_amdgcn_s_barrier();
        asm volatile("" ::: "memory");
        __builtin_amdgcn_s_setprio(1);
        #pragma unroll
        for (int ks = 0; ks < 2; ++ks)
            #pragma unroll
            for (int mi = 0; mi < 4; ++mi)
                #pragma unroll
                for (int nj = 0; nj < 2; ++nj)
                    acc[4 + mi][nj] = __builtin_amdgcn_mfma_f32_16x16x32_bf16(
                        a1[mi][ks], b0[nj][ks], acc[4 + mi][nj], 0, 0, 0);
        __builtin_amdgcn_s_setprio(0);
    }
#undef PH_IN

    if (bias) {
        #pragma unroll
        for (int mi = 0; mi < 8; ++mi) {
            int row0 = bm + wm + mi * 16 + quad * 4;
            #pragma unroll
            for (int nj = 0; nj < 4; ++nj) {
                int col = bn + wn + nj * 16 + l16;
                float bv = bias[col];
                #pragma unroll
                for (int r = 0; r < 4; ++r) {
                    size_t idx = (size_t)(row0 + r) * N + col;
                    float cc = acc[mi][nj][r] + bv;
                    if (relu) cc = fmaxf(cc, 0.f);
                    if (res)  cc += res[idx];
                    if (outF) outF[idx] = cc;
                    if (outB) outB[idx] = (__bf16)cc;
                }
            }
        }
    } else {
        __bf16* po = outB + (size_t)bz * M * N;
        #pragma unroll
        for (int mi = 0; mi < 8; ++mi) {
            int row0 = bm + wm + mi * 16 + quad * 4;
            #pragma unroll
            for (int nj = 0; nj < 4; ++nj) {
                int col = bn + wn + nj * 16 + l16;
                #pragma unroll
                for (int r = 0; r < 4; ++r)
                    po[(size_t)(row0 + r) * N + col] = (__bf16)acc[mi][nj][r];
            }
        }
    }
}

// ---------------- split-K reduce: out = x2 + bias + sum of 4 bf16 partials -
__global__ __launch_bounds__(256)
void reduce_proj(const __bf16* __restrict__ pbuf, const float* __restrict__ x2,
                 const float* __restrict__ bias, float* __restrict__ out) {
    const size_t MN = (size_t)4096 * 1024;
    size_t i = (size_t)blockIdx.x * 256 + threadIdx.x;   // float4 index
    float4 r = ((const float4*)x2)[i];
    float4 bb = ((const float4*)bias)[i & 255];
    float acc0 = r.x + bb.x, acc1 = r.y + bb.y;
    float acc2 = r.z + bb.z, acc3 = r.w + bb.w;
    for (int k = 0; k < 4; k++) {
        bf16x4 pv = *(const bf16x4*)&pbuf[k * MN + i * 4];
        acc0 += (float)pv[0]; acc1 += (float)pv[1];
        acc2 += (float)pv[2]; acc3 += (float)pv[3];
    }
    float4 o = {acc0, acc1, acc2, acc3};
    ((float4*)out)[i] = o;
}

// ---------------- bf16 MFMA GEMM (BM=128, BN=64) — ws-fallback only --------
__global__ __launch_bounds__(256)
void gemm_bt_n64(const __bf16* __restrict__ A, const __bf16* __restrict__ Bt,
                 const float* __restrict__ bias, const float* __restrict__ res,
                 float* __restrict__ outF, __bf16* __restrict__ outB,
                 int M, int N, int K, int relu) {
    __shared__ __align__(16) __bf16 sA[128][40];
    __shared__ __align__(16) __bf16 sB[64][40];
    int tid  = threadIdx.x;
    int lane = tid & 63, wave = tid >> 6;
    int quad = lane >> 4, l16 = lane & 15;
    int bm = blockIdx.y * 128, bn = blockIdx.x * 64;
    int wm = (wave & 1) * 64, wn = (wave >> 1) * 32;
    floatx4 acc[4][2] = {};

    int srow = tid >> 2;
    int scol = (tid & 3) * 8;
    const __bf16* gA = &A[(size_t)(bm + srow) * K + scol];
    const __bf16* gB = &Bt[(size_t)(bn + srow) * K + scol];

    uint4 ra0 = *(const uint4*)gA;
    uint4 ra1 = *(const uint4*)(gA + (size_t)64 * K);
    uint4 rb0 = *(const uint4*)gB;

    for (int kk = 0; kk < K; kk += 32) {
        __syncthreads();
        *(uint4*)&sA[srow][scol]      = ra0;
        *(uint4*)&sA[srow + 64][scol] = ra1;
        *(uint4*)&sB[srow][scol]      = rb0;
        __syncthreads();
        {
            int kn = (kk + 32 < K) ? kk + 32 : kk;
            ra0 = *(const uint4*)(gA + kn);
            ra1 = *(const uint4*)(gA + kn + (size_t)64 * K);
            rb0 = *(const uint4*)(gB + kn);
        }
        bf16x8 af[4], bfr[2];
        for (int i = 0; i < 4; i++)
            af[i] = *(const bf16x8*)&sA[wm + i * 16 + l16][quad * 8];
        for (int j = 0; j < 2; j++)
            bfr[j] = *(const bf16x8*)&sB[wn + j * 16 + l16][quad * 8];
        for (int i = 0; i < 4; i++)
            for (int j = 0; j < 2; j++)
                acc[i][j] = __builtin_amdgcn_mfma_f32_16x16x32_bf16(
                    af[i], bfr[j], acc[i][j], 0, 0, 0);
    }

    for (int i = 0; i < 4; i++) {
        int row0 = bm + wm + i * 16 + quad * 4;
        for (int j = 0; j < 2; j++) {
            int col = bn + wn + j * 16 + l16;
            float bv = bias[col];
            for (int r = 0; r < 4; r++) {
                size_t idx = (size_t)(row0 + r) * N + col;
                float c = acc[i][j][r] + bv;
                if (relu) c = fmaxf(c, 0.f);
                if (res)  c += res[idx];
                if (outF) outF[idx] = c;
                if (outB) outB[idx] = (__bf16)c;
            }
        }
    }
}

// ---------------- flash attention: CU-balanced complementary pairs --------
// grid 512: i -> XCD c=i&7, m=i>>3. Dispatch model: XCD x receives m=j in
// order; CU k hosts j=k and j=k+32. pair=(j<8)?j:23-j -> CU runs pairs
// (q, 15-q): 49 iterations on EVERY CU. Waves 0-3 heavy qt_h=31-pair,
// waves 4-7 light=pair (16 rows/wave); light group skips past-diagonal
// tiles (wave-uniform, barriers outside). Softmax fixed-max exp2,
// wave-private sP. T5 setprio(1) around QK/PV MFMA clusters.
__global__ __launch_bounds__(512)
void attn_kernel(const __bf16* __restrict__ qkv, const float* __restrict__ x,
                 float* __restrict__ x2) {
    __shared__ __align__(16) __bf16 sK[2][64][72];
    __shared__ __align__(16) __bf16 sVt[2][64][72];
    __shared__ __align__(16) __bf16 sP[8][16][72];
    const int tid  = threadIdx.x;
    const int lane = tid & 63, wave = tid >> 6;
    const int quad = lane >> 4, l16 = lane & 15;

    int i = blockIdx.x;
    int c = i & 7, m = i >> 3;
    const int bh   = (m & 3) * 8 + c;          // 0..31, XCD-pinned
    const int j_   = m >> 2;                   // 0..15 dispatch-order index
    const int pair = (j_ < 8) ? j_ : 23 - j_;  // CU-balanced bijection
    const int qt_h = 31 - pair;                // heavy q-tile, 16..31
    const int h    = bh & (NH - 1);
    const int b    = bh >> 4;
    const size_t rowbase = (size_t)b * T_LEN;

    const int g  = wave >> 2;                  // 0 = heavy group, 1 = light
    const int wg = wave & 3;
    const int qt = g ? pair : qt_h;            // this group's q-tile
    const int qrow = qt * 64 + wg * 16;        // this wave's 16 q rows
    const int dt   = qt;                       // group's diagonal K-tile

    const float kQScale = 0.125f * 1.44269504088896f;
    bf16x8 ones;
    for (int j = 0; j < 8; j++) ones[j] = (__bf16)1.0f;

    // staging: 512 threads cover 64 keys x 8 chunks, one uint4 each
    const int key0 = tid >> 3, m8 = tid & 7;
    const __bf16* kp0 = qkv + (rowbase + key0) * 3072 + h * HD + m8 * 8 + 1024;
    const int pc0 = ((key0 >> 3) ^ m8) * 8 + (key0 & 7);

    bf16x8 qf[2];
    for (int ks = 0; ks < 2; ks++) {
        bf16x8 raw = *(const bf16x8*)&qkv[(rowbase + qrow + l16) * 3072
                                          + h * HD + ks * 32 + quad * 8];
        for (int j = 0; j < 8; j++)
            qf[ks][j] = (__bf16)((float)raw[j] * kQScale);
    }

    floatx4 o[4] = {}, ol = {};

    const int ntiles = qt_h + 1;               // 17..32
    const size_t TSTEP = (size_t)64 * 3072;

    // prologue: tile 0 -> regs -> buf0 ; tile 1 -> regs ; barrier
    uint4 kr0 = *(const uint4*)kp0;
    uint4 vr0 = *(const uint4*)(kp0 + 1024);
    {
        *(uint4*)&sK[0][key0][m8 * 8] = kr0;
        bf16x8 v0 = *(bf16x8*)&vr0;
        for (int j = 0; j < 8; j++) sVt[0][m8 * 8 + j][pc0] = v0[j];
    }
    kr0 = *(const uint4*)(kp0 + TSTEP);            // ntiles >= 17 always
    vr0 = *(const uint4*)(kp0 + TSTEP + 1024);
    __syncthreads();

    for (int kt = 0; kt < ntiles; kt++) {
        const int cur = kt & 1, nxt = cur ^ 1;
        if (kt + 1 < ntiles) {
            *(uint4*)&sK[nxt][key0][m8 * 8] = kr0;
            bf16x8 v0 = *(bf16x8*)&vr0;
            for (int j = 0; j < 8; j++) sVt[nxt][m8 * 8 + j][pc0] = v0[j];
            size_t offn = (size_t)((kt + 2 < ntiles) ? kt + 2 : kt + 1) * TSTEP;
            kr0 = *(const uint4*)(kp0 + offn);
            vr0 = *(const uint4*)(kp0 + offn + 1024);
        }

        if (kt <= dt) {
            // S = Q K^T (exp2 domain) from buf[cur]
            floatx4 s_acc[4] = {};
            __builtin_amdgcn_s_setprio(1);
            for (int jt = 0; jt < 4; jt++)
                for (int ks = 0; ks < 2; ks++) {
                    bf16x8 kf = *(const bf16x8*)&sK[cur][jt * 16 + l16]
                                                  [ks * 32 + quad * 8];
                    s_acc[jt] = __builtin_amdgcn_mfma_f32_16x16x32_bf16(
                        qf[ks], kf, s_acc[jt], 0, 0, 0);
                }
            __builtin_amdgcn_s_setprio(0);

            // P = exp2(min(s,30)); mask only on this group's diagonal tile.
            if (kt == dt) {
                const int tq0 = qrow + quad * 4;
                const int k0 = kt * 64;
                for (int jt = 0; jt < 4; jt++) {
                    int key = k0 + jt * 16 + l16;
                    for (int r = 0; r < 4; r++) {
                        float sv = (key <= tq0 + r) ? s_acc[jt][r] : -1e30f;
                        float pv = __builtin_amdgcn_exp2f(fminf(sv, 30.f));
                        sP[wave][quad * 4 + r][jt * 16 + l16] = (__bf16)pv;
                    }
                }
            } else {
                for (int jt = 0; jt < 4; jt++)
                    for (int r = 0; r < 4; r++) {
                        float pv = __builtin_amdgcn_exp2f(fminf(s_acc[jt][r], 30.f));
                        sP[wave][quad * 4 + r][jt * 16 + l16] = (__bf16)pv;
                    }
            }
            // sP wave-private: lgkmcnt ordering suffices, no barrier.

            for (int kp = 0; kp < 2; kp++) {
                bf16x8 pf = *(const bf16x8*)&sP[wave][l16][kp * 32 + quad * 8];
                __builtin_amdgcn_s_setprio(1);
                ol = __builtin_amdgcn_mfma_f32_16x16x32_bf16(pf, ones, ol, 0, 0, 0);
                for (int jt2 = 0; jt2 < 4; jt2++) {
                    int d = jt2 * 16 + l16;
                    int pg = (kp * 4 + quad) ^ (d >> 3);
                    bf16x8 vf = *(const bf16x8*)&sVt[cur][d][pg * 8];
                    o[jt2] = __builtin_amdgcn_mfma_f32_16x16x32_bf16(
                        pf, vf, o[jt2], 0, 0, 0);
                }
                __builtin_amdgcn_s_setprio(0);
            }
        }
        __syncthreads();   // all waves done reading cur & writing nxt
    }

    float inv[4];
    for (int r = 0; r < 4; r++) inv[r] = __builtin_amdgcn_rcpf(ol[r]);
    for (int jt2 = 0; jt2 < 4; jt2++) {
        for (int r = 0; r < 4; r++) {
            int tq  = qrow + quad * 4 + r;
            int col = h * HD + jt2 * 16 + l16;
            size_t gi = (rowbase + tq) * EMB + col;
            x2[gi] = x[gi] + o[jt2][r] * inv[r];
        }
    }
}

// ---------------------------------------------------------------------------
extern "C" void kernel_launch(void* const* d_in, const int* in_sizes, int n_in,
                              void* d_out, int out_size, void* d_ws, size_t ws_size,
                              hipStream_t stream) {
    const float* x      = (const float*)d_in[0];
    const float* ln1_s  = (const float*)d_in[1];
    const float* ln1_b  = (const float*)d_in[2];
    const float* w_qkv  = (const float*)d_in[3];
    const float* b_qkv  = (const float*)d_in[4];
    const float* ln2_s  = (const float*)d_in[5];
    const float* ln2_b  = (const float*)d_in[6];
    const float* w_fc   = (const float*)d_in[7];
    const float* b_fc   = (const float*)d_in[8];
    const float* w_proj = (const float*)d_in[9];
    const float* b_proj = (const float*)d_in[10];
    float* out = (float*)d_out;

    const int M = 2 * T_LEN;  // 4096 rows
    char* ws = (char*)d_ws;
    size_t off = 0;
    auto alloc = [&](size_t bytes) {
        void* p = ws + off; off += (bytes + 255) & ~(size_t)255; return p;
    };
    // alive through proj:
    __bf16* wpj_t  = (__bf16*)alloc((size_t)1024 * 4096 * 2);
    float*  x2     = (float*) alloc((size_t)M * 1024 * 4);
    __bf16* hfc    = (__bf16*)alloc((size_t)M * 4096 * 2);
    size_t mark = off;                    // dead-by-proj region starts here
    __bf16* wqkv_t = (__bf16*)alloc((size_t)3072 * 1024 * 2);
    __bf16* wfc_t  = (__bf16*)alloc((size_t)4096 * 1024 * 2);
    __bf16* h1     = (__bf16*)alloc((size_t)M * 1024 * 2);
    __bf16* h2     = (__bf16*)alloc((size_t)M * 1024 * 2);
    __bf16* qkvb   = (__bf16*)alloc((size_t)M * 3072 * 2);
    // split-K bf16 partials overlay the dead region.
    __bf16* pbuf = (__bf16*)(ws + mark);
    size_t need = mark + (size_t)4 * M * 1024 * 2;
    bool can_split = ws_size >= need;

    // LN1 + 3x weight transpose fused (independent work, one launch)
    prep_kernel<<<15360, 256, 0, stream>>>(x, ln1_s, ln1_b, h1,
                                           w_qkv, wqkv_t, w_fc, wfc_t,
                                           w_proj, wpj_t);

    // qkv = LN1(x) @ w_qkv + b_qkv -> bf16 ; grid 16x12 flattened (192)
    gemm256<<<192, 512, 0, stream>>>(
        h1, wqkv_t, b_qkv, nullptr, nullptr, qkvb, M, 3072, 1024, 1024, 0,
        12, 1);

    attn_kernel<<<512, 512, 0, stream>>>(qkvb, x, x2);

    ln_kernel<<<M, 256, 0, stream>>>(x2, ln2_s, ln2_b, h2);

    // hfc = relu(h2 @ w_fc + b_fc) -> bf16 ; grid 16x16 flattened (256)
    gemm256<<<256, 512, 0, stream>>>(
        h2, wfc_t, b_fc, nullptr, nullptr, hfc, M, 4096, 1024, 1024, 1,
        16, 1);

    if (can_split) {
        // proj partials: 4 K-chunks of 1024, grid 16x4x4 flattened (256)
        gemm256<<<256, 512, 0, stream>>>(
            hfc, wpj_t, nullptr, nullptr, nullptr, pbuf, M, 1024, 4096, 1024, 0,
            4, 4);
        reduce_proj<<<(M * 1024 / 4) / 256, 256, 0, stream>>>(
            pbuf, x2, b_proj, out);
    } else {
        gemm_bt_n64<<<dim3(1024 / 64, M / 128), 256, 0, stream>>>(
            hfc, wpj_t, b_proj, x2, out, nullptr, M, 1024, 4096, 0);
    }
}